// Round 7
// baseline (844.428 us; speedup 1.0000x reference)
//
#include <hip/hip_runtime.h>
#include <math.h>

#define BATCH 2048
#define DIN 768
#define DICT 24576
#define KM 32
#define KA 512
#define NPT 48            // DICT / 512 elements per thread
#define L1_COEFF 0.001f
#define AUX_PENALTY 0.03125f
#define CAND_MAX 128
#define CAND_DELTA 0.08f
#define AUX_SPLIT 8       // split-K factor for the aux GEMM
#define SAUX 18432        // compact-acts row stride (bf16); WETF region reuse
#define AGB ((DIN/128)*(BATCH/128)*AUX_SPLIT)   // 768 aux-gemm blocks

typedef __attribute__((ext_vector_type(8))) short bf16x8;
typedef __attribute__((ext_vector_type(8))) unsigned short u16x8;
typedef __attribute__((ext_vector_type(4))) float f32x4;

// ---------------- ws layout (float slots) ----------------
constexpr size_t WS_XENC   = 0;                              // BATCH*DIN f32 (x_enc; later aux split-7 buffer)
constexpr size_t WS_YN     = WS_XENC + (size_t)BATCH*DIN;    // BATCH*DIN (later aux split-6 buffer)
constexpr size_t WS_YMEAN  = WS_YN + (size_t)BATCH*DIN;      // BATCH
constexpr size_t WS_YSTD   = WS_YMEAN + BATCH;               // BATCH
constexpr size_t WS_RES    = WS_YSTD + BATCH;                // BATCH*DIN
constexpr size_t WS_NSEL   = WS_RES + (size_t)BATCH*DIN;     // BATCH (unused)
constexpr size_t WS_SEL    = WS_NSEL + BATCH;                // BATCH*KM (int)
constexpr size_t WS_SELV   = WS_SEL + (size_t)BATCH*KM;      // BATCH*KM (float, exact vals)
constexpr size_t WS_COLACT = WS_SELV + (size_t)BATCH*KM;     // DICT (int, cleared in prep_k)
constexpr size_t WS_ACC    = WS_COLACT + DICT;               // 8 (cleared in prep_k)
constexpr size_t WS_DB     = WS_ACC + 8;                     // DICT/32 words (dead bitmap)
constexpr size_t WS_XEB    = WS_DB + DICT/32;                // BATCH*DIN bf16 -> /2 slots
constexpr size_t WS_WETF   = WS_XEB + (size_t)BATCH*DIN/2;   // DICT*DIN f32 (Wenc^T; reused as compact aux acts)
constexpr size_t WS_WETB   = WS_WETF + (size_t)DICT*DIN;     // DICT*DIN bf16 (Wenc^T; later aux split bufs 0..5)
constexpr size_t WS_WDB    = WS_WETB + (size_t)DICT*DIN/2;   // DIN*DICT bf16 (Wdec^T, compacted in place)
// small int arrays live in the XEB region (xeb is dead after gemm_mfma):
constexpr size_t WS_DPREF  = WS_XEB + DICT/32;               // DICT/32 ints (exclusive prefix = rank base)
constexpr size_t WS_META   = WS_XEB + 2*(DICT/32);           // 8 ints: [0]=ND [1]=NDpad [2]=NKT [3]=chunk
// ACC: 0 l2_sum, 1 l1_sum, 2 l0_sum, 3 aux_sq, 4 numdead, 5 anydead(int)

__device__ __forceinline__ unsigned short f2b(float f){   // RNE fp32 -> bf16
    unsigned u = __float_as_uint(f);
    return (unsigned short)((u + 0x7fffu + ((u >> 16) & 1u)) >> 16);
}
__device__ __forceinline__ float b2f(unsigned short h){ return __uint_as_float(((unsigned)h) << 16); }

__device__ __forceinline__ void gld_lds16(const void* g, void* l){
    __builtin_amdgcn_global_load_lds(
        (const __attribute__((address_space(1))) unsigned int*)g,
        (__attribute__((address_space(3))) unsigned int*)l, 16, 0, 0);
}

// wave-uniform count (from ballot/popc) -> block total; ping-pong parity buffer
__device__ __forceinline__ int blk_count512_w(int cw, int* s16, int par){
    if ((threadIdx.x & 63) == 0) s16[par*8 + (threadIdx.x >> 6)] = cw;
    __syncthreads();
    int tot = 0;
    #pragma unroll
    for (int w=0; w<8; w++) tot += s16[par*8+w];
    return tot;
}
__device__ __forceinline__ float blk_sum512(float v, float* s16, int par){
    #pragma unroll
    for (int off=32; off; off>>=1) v += __shfl_down(v, off);
    if ((threadIdx.x & 63) == 0) s16[par*8 + (threadIdx.x >> 6)] = v;
    __syncthreads();
    float t = 0.f;
    #pragma unroll
    for (int w=0; w<8; w++) t += s16[par*8+w];
    return t;
}
__device__ __forceinline__ float blk_sum256(float v, float* s8, int par){
    #pragma unroll
    for (int off=32; off; off>>=1) v += __shfl_down(v, off);
    if ((threadIdx.x & 63) == 0) s8[par*4 + (threadIdx.x >> 6)] = v;
    __syncthreads();
    float t = 0.f;
    #pragma unroll
    for (int w=0; w<4; w++) t += s8[par*4+w];
    return t;
}

// ---------------- kernel A+P: normalize rows AND both weight transposes ------
__global__ __launch_bounds__(256) void prep_k(const float* __restrict__ x,
        const float* __restrict__ y, const float* __restrict__ bdec,
        const float* __restrict__ We, const float* __restrict__ Wd,
        float* __restrict__ Tf, unsigned short* __restrict__ Tb,
        unsigned short* __restrict__ Td, float* __restrict__ ws){
    __shared__ float s8[8];
    __shared__ float t1[32][33];
    __shared__ float t2[32][33];
    const int tid = threadIdx.x;
    if (blockIdx.x < 2*BATCH){
        int b = blockIdx.x; bool isy = b >= BATCH; int row = isy ? b - BATCH : b;
        if (b < 8){   // clear colact + ACC (read only by later launches)
            float* dst = ws + WS_COLACT;
            for (int i = b*256 + tid; i < DICT + 8; i += 2048) dst[i] = 0.f;
        }
        const float* src = (isy ? y : x) + (size_t)row*DIN;
        float v0 = src[tid], v1 = src[tid+256], v2 = src[tid+512];
        float s = blk_sum256(v0+v1+v2, s8, 0);
        float mean = s * (1.f/(float)DIN);
        float d0 = v0-mean, d1 = v1-mean, d2 = v2-mean;
        float vs = blk_sum256(d0*d0+d1*d1+d2*d2, s8, 1);
        float sd = sqrtf(vs / (float)(DIN-1));
        float inv = 1.f / (sd + 1e-5f);
        if (isy){
            float* yn = ws + WS_YN + (size_t)row*DIN;
            yn[tid] = d0*inv; yn[tid+256] = d1*inv; yn[tid+512] = d2*inv;
            if (tid==0){ ws[WS_YMEAN+row] = mean; ws[WS_YSTD+row] = sd; }
        } else {
            float* xe = ws + WS_XENC + (size_t)row*DIN;
            unsigned short* xeb = (unsigned short*)(ws + WS_XEB) + (size_t)row*DIN;
            float e0 = d0*inv - bdec[tid];
            float e1 = d1*inv - bdec[tid+256];
            float e2 = d2*inv - bdec[tid+512];
            xe[tid] = e0; xe[tid+256] = e1; xe[tid+512] = e2;
            xeb[tid] = f2b(e0); xeb[tid+256] = f2b(e1); xeb[tid+512] = f2b(e2);
        }
    } else {
        int t = blockIdx.x - 2*BATCH;
        int bx = t % (DICT/32), by = t / (DICT/32);
        int a0 = bx*32, k0 = by*32;                 // a0 over DICT, k0 over DIN
        int r = tid >> 5, c = tid & 31;
        #pragma unroll
        for (int rr=r; rr<32; rr+=8){
            t1[rr][c] = We[(size_t)(k0+rr)*DICT + a0 + c];   // Wenc[k][n]
            t2[rr][c] = Wd[(size_t)(a0+rr)*DIN + k0 + c];    // Wdec[j][n]
        }
        __syncthreads();
        #pragma unroll
        for (int rr=r; rr<32; rr+=8){
            float v = t1[c][rr];                 // = Wenc[k0+c][a0+rr]
            Tf[(size_t)(a0+rr)*DIN + k0 + c] = v;
            Tb[(size_t)(a0+rr)*DIN + k0 + c] = f2b(v);
            Td[(size_t)(k0+rr)*DICT + a0 + c] = f2b(t2[c][rr]);  // Td[n][j]=Wdec[j][n]
        }
    }
}

// ---------------- kernel B: 256x256-tile deep-pipelined bf16 MFMA GEMM -------
// 8 waves (2x4), 128KB double-buffered LDS, proven xor-8 row swizzle (0-conflict).
// Per K-tile: 4 phases of {2 gld prefetch(next tile) + ds_read frags + barrier
// + setprio(1) + 16 MFMA + setprio(0)}; tile boundary = vmcnt(0)+barrier only.
// Loads for tile t+1 are issued >=3 phases ahead -> latency hidden (T3/T4;
// 256^2 needs the explicit pipeline: 1 block/CU, no implicit wave overlap).
__global__ __launch_bounds__(512, 2) void gemm_mfma(const unsigned short* __restrict__ Abf,
        const unsigned short* __restrict__ Bbf, unsigned short* __restrict__ C){
    __shared__ __align__(16) unsigned short As2[2][16384];   // 2 x 256rows x 64
    __shared__ __align__(16) unsigned short Bs2[2][16384];
    const int tid = threadIdx.x;
    const int w = tid >> 6, lane = tid & 63;
    const int wr = w >> 2, wc = w & 3;            // 2 x 4 wave grid
    const int g = blockIdx.x;
    const int xcd = g & 7;
    const int s_ = g >> 3;                        // 0..95
    const int m_t = s_ & 7;                       // 8 M-tiles of 256
    const int n_t = xcd + 8*(s_ >> 3);            // 12 n-panels per XCD
    const int m0 = m_t*256, n0 = n_t*256;
    const int srow = lane >> 3;                   // 0..7 row within staging stripe
    const int schunk = (lane & 7) ^ srow;         // source chunk (xor swizzle)
    const int l15 = lane & 15, l4 = lane >> 4;

    f32x4 acc[8][4];
    #pragma unroll
    for (int i=0;i<8;i++)
        #pragma unroll
        for (int j=0;j<4;j++) acc[i][j] = (f32x4){0.f,0.f,0.f,0.f};

    // stage stripe q (0..3) of tile kt into buffer b: wave w covers rows 8*(w*4+q)+srow
    #define STAGE_Q(b,kt,q) { \
        int sa = w*4 + (q); \
        gld_lds16(Abf + (size_t)(m0 + 8*sa + srow)*DIN + (kt) + schunk*8, &As2[b][8*sa*64]); \
        gld_lds16(Bbf + (size_t)(n0 + 8*sa + srow)*DIN + (kt) + schunk*8, &Bs2[b][8*sa*64]); }

    // prologue: stage tile 0 fully into buf 0
    #pragma unroll
    for (int q=0;q<4;q++) STAGE_Q(0, 0, q);
    asm volatile("s_waitcnt vmcnt(0)" ::: "memory");
    __builtin_amdgcn_s_barrier();

    for (int t = 0; t < 12; ++t){
        const int cur = t & 1, nb = cur ^ 1;
        const unsigned short* Ac = As2[cur];
        const unsigned short* Bc = Bs2[cur];
        const int ktn = (t+1)*64;
        const bool more = t < 11;
        bf16x8 af[4], bfr[4];
        // ---- phase 0: kk=0, A i=0..3 (+ B for kk=0) ----
        if (more) STAGE_Q(nb, ktn, 0);
        {
            int ch = l4;                               // kk=0 chunks 0..3
            #pragma unroll
            for (int j=0;j<4;j++){
                int row = wc*64 + j*16 + l15;
                bfr[j] = *(const bf16x8*)&Bc[row*64 + ((ch ^ (row&7))<<3)];
            }
            #pragma unroll
            for (int i=0;i<4;i++){
                int row = wr*128 + i*16 + l15;
                af[i] = *(const bf16x8*)&Ac[row*64 + ((ch ^ (row&7))<<3)];
            }
        }
        __builtin_amdgcn_s_barrier();
        __builtin_amdgcn_s_setprio(1);
        #pragma unroll
        for (int i=0;i<4;i++)
            #pragma unroll
            for (int j=0;j<4;j++)
                acc[i][j] = __builtin_amdgcn_mfma_f32_16x16x32_bf16(af[i], bfr[j], acc[i][j], 0,0,0);
        __builtin_amdgcn_s_setprio(0);
        // ---- phase 1: kk=0, A i=4..7 (reuse bfr) ----
        if (more) STAGE_Q(nb, ktn, 1);
        {
            int ch = l4;
            #pragma unroll
            for (int i=0;i<4;i++){
                int row = wr*128 + (i+4)*16 + l15;
                af[i] = *(const bf16x8*)&Ac[row*64 + ((ch ^ (row&7))<<3)];
            }
        }
        __builtin_amdgcn_s_barrier();
        __builtin_amdgcn_s_setprio(1);
        #pragma unroll
        for (int i=0;i<4;i++)
            #pragma unroll
            for (int j=0;j<4;j++)
                acc[i+4][j] = __builtin_amdgcn_mfma_f32_16x16x32_bf16(af[i], bfr[j], acc[i+4][j], 0,0,0);
        __builtin_amdgcn_s_setprio(0);
        // ---- phase 2: kk=32, A i=0..3 (+ B for kk=32) ----
        if (more) STAGE_Q(nb, ktn, 2);
        {
            int ch = 4 + l4;                           // kk=32 chunks 4..7
            #pragma unroll
            for (int j=0;j<4;j++){
                int row = wc*64 + j*16 + l15;
                bfr[j] = *(const bf16x8*)&Bc[row*64 + ((ch ^ (row&7))<<3)];
            }
            #pragma unroll
            for (int i=0;i<4;i++){
                int row = wr*128 + i*16 + l15;
                af[i] = *(const bf16x8*)&Ac[row*64 + ((ch ^ (row&7))<<3)];
            }
        }
        __builtin_amdgcn_s_barrier();
        __builtin_amdgcn_s_setprio(1);
        #pragma unroll
        for (int i=0;i<4;i++)
            #pragma unroll
            for (int j=0;j<4;j++)
                acc[i][j] = __builtin_amdgcn_mfma_f32_16x16x32_bf16(af[i], bfr[j], acc[i][j], 0,0,0);
        __builtin_amdgcn_s_setprio(0);
        // ---- phase 3: kk=32, A i=4..7 ----
        if (more) STAGE_Q(nb, ktn, 3);
        {
            int ch = 4 + l4;
            #pragma unroll
            for (int i=0;i<4;i++){
                int row = wr*128 + (i+4)*16 + l15;
                af[i] = *(const bf16x8*)&Ac[row*64 + ((ch ^ (row&7))<<3)];
            }
        }
        __builtin_amdgcn_s_barrier();
        __builtin_amdgcn_s_setprio(1);
        #pragma unroll
        for (int i=0;i<4;i++)
            #pragma unroll
            for (int j=0;j<4;j++)
                acc[i+4][j] = __builtin_amdgcn_mfma_f32_16x16x32_bf16(af[i], bfr[j], acc[i+4][j], 0,0,0);
        __builtin_amdgcn_s_setprio(0);
        // ---- tile boundary: drain next-tile loads (issued ~4 phases ago) ----
        asm volatile("s_waitcnt vmcnt(0)" ::: "memory");
        __builtin_amdgcn_s_barrier();
    }
    #undef STAGE_Q
    // C/D layout: col = lane&15, row = (lane>>4)*4 + reg.  +0.0f kills -0.
    #pragma unroll
    for (int i=0;i<8;i++){
        #pragma unroll
        for (int r=0;r<4;r++){
            int m = m0 + wr*128 + i*16 + l4*4 + r;
            unsigned short* crow = C + (size_t)m*DICT + n0 + wc*64 + l15;
            #pragma unroll
            for (int j=0;j<4;j++)
                crow[j*16] = f2b(fmaxf(acc[i][j][r], 0.f) + 0.0f);
        }
    }
}

// ---------------- kernel C1: block radix -> exact refine -> top-32 -----------
// (proven 147µs structure; NO device fences — kernel boundary provides the
// release/acquire for colact -> deadscan_k.)
__global__ __launch_bounds__(512) void topk_main(const unsigned short* __restrict__ actsb,
        const float* __restrict__ WeTf, const float* __restrict__ Wdec,
        const float* __restrict__ bdec, float* __restrict__ ws,
        float* __restrict__ ypred_out){
    const int row = blockIdx.x, tid = threadIdx.x;
    const int lane = tid & 63, wid = tid >> 6;
    __shared__ int   s_i16[16];
    __shared__ float s_f16[16];
    __shared__ float s_x[DIN];
    __shared__ int   s_ci[CAND_MAX];
    __shared__ float s_cv[CAND_MAX];
    __shared__ int   s_li[KM];
    __shared__ float s_lv[KM];
    __shared__ int   s_n, s_m;
    const unsigned short* arow = actsb + (size_t)row * DICT;
    const float* xrow = ws + WS_XENC + (size_t)row * DIN;
    unsigned short h[NPT];
    #pragma unroll
    for (int i=0;i<6;i++){
        u16x8 v = *(const u16x8*)&arow[i*4096 + tid*8];
        #pragma unroll
        for (int e=0;e<8;e++) h[i*8+e] = v[e];
    }
    s_x[tid] = xrow[tid];
    if (tid < DIN-512) s_x[tid+512] = xrow[tid+512];
    if (tid == 0){ s_n = 0; s_m = 0; }

    // 15-bit block radix on bf16 pattern: prefix = 32nd-largest stored value.
    int par = 0;
    unsigned prefix = 0;
    for (int bit=14; bit>=0; bit--){
        unsigned cand = prefix | (1u<<bit);
        int c = 0;
        #pragma unroll
        for (int q=0;q<NPT;q++) c += (int)__popcll(__ballot((unsigned)h[q] >= cand));
        int tot = blk_count512_w(c, s_i16, par); par ^= 1;
        if (tot >= KM) prefix = cand;
    }
    float tc = b2f((unsigned short)prefix) - CAND_DELTA;  // candidate threshold
    #pragma unroll
    for (int q=0;q<NPT;q++){
        if (b2f(h[q]) > tc){
            int p = atomicAdd(&s_n, 1);
            if (p < CAND_MAX) s_ci[p] = (q>>3)*4096 + tid*8 + (q&7);
        }
    }
    __syncthreads();
    int nc = s_n; if (nc > CAND_MAX) nc = CAND_MAX;
    // exact fp32 recompute of candidates (wave per candidate, strided)
    for (int c = wid; c < nc; c += 8){
        const float* wr = WeTf + (size_t)s_ci[c]*DIN;
        float p = 0.f;
        #pragma unroll
        for (int t=0; t<12; t++) p = fmaf(s_x[lane + 64*t], wr[lane + 64*t], p);
        #pragma unroll
        for (int off=32; off; off>>=1) p += __shfl_down(p, off);
        if (lane == 0) s_cv[c] = fmaxf(p, 0.f);
    }
    __syncthreads();
    // exact top-32 among candidates, stable (value desc, index asc)
    if (tid < nc){
        float vi = s_cv[tid]; int ii = s_ci[tid];
        int rank = 0;
        for (int j=0; j<nc; j++){
            float vj = s_cv[j];
            rank += (vj > vi) || (vj == vi && s_ci[j] < ii);
        }
        if (rank < KM){
            int p = atomicAdd(&s_m, 1);
            s_li[p] = ii; s_lv[p] = vi;
        }
    }
    __syncthreads();
    if (tid < KM){
        ((int*)ws)[WS_COLACT + s_li[tid]] = 1;
        ((int*)ws)[WS_SEL  + (size_t)row*KM + tid] = s_li[tid];
        ws[WS_SELV + (size_t)row*KM + tid] = s_lv[tid];
    }
    if (tid == 0){
        float l1 = 0.f; int l0 = 0;
        for (int l=0;l<KM;l++){ l1 += s_lv[l]; l0 += (s_lv[l] > 0.f); }
        atomicAdd(&ws[WS_ACC+1], l1);
        atomicAdd(&ws[WS_ACC+2], (float)l0);
    }
    __syncthreads();
    float ym = ws[WS_YMEAN+row], ys = ws[WS_YSTD+row];
    float l2loc = 0.f;
    for (int c = tid; c < DIN; c += 512){
        float acc = bdec[c];
        #pragma unroll 4
        for (int l=0;l<KM;l++) acc = fmaf(s_lv[l], Wdec[(size_t)s_li[l]*DIN + c], acc);
        float ynv = ws[WS_YN + (size_t)row*DIN + c];
        float d = acc - ynv;
        l2loc += d*d;
        ws[WS_RES + (size_t)row*DIN + c] = ynv - acc;
        ypred_out[(size_t)row*DIN + c] = fmaf(acc, ys, ym);
    }
    float l2t = blk_sum512(l2loc, s_f16, 0);
    if (tid==0) atomicAdd(&ws[WS_ACC+0], l2t);
}

// ---------------- kernel D+S: dead bookkeeping + popcount prefix scan --------
__global__ __launch_bounds__(768) void deadscan_k(const float* __restrict__ nb,
        float* __restrict__ ws){
    __shared__ int s[DICT/32];
    __shared__ int c12[12];
    const int t = threadIdx.x;
    const int* colact = (const int*)ws + WS_COLACT;
    unsigned bits = 0; int cgt = 0;
    const int base = t*32;
    #pragma unroll 8
    for (int b=0;b<32;b++){
        int j = base + b;
        float nbn = colact[j] ? 0.f : nb[j] + 1.f;
        bits |= (nbn >= 100.f ? 1u : 0u) << b;
        cgt  += (nbn > 100.f) ? 1 : 0;
    }
    ((unsigned*)(ws + WS_DB))[t] = bits;
    int pc = __popc(bits);
    s[t] = pc;
    #pragma unroll
    for (int off=32; off; off>>=1) cgt += __shfl_down(cgt, off);
    if ((t & 63) == 0) c12[t >> 6] = cgt;
    __syncthreads();
    for (int off=1; off<DICT/32; off<<=1){
        int v = (t >= off) ? s[t-off] : 0;
        __syncthreads();
        s[t] += v;
        __syncthreads();
    }
    ((int*)(ws + WS_DPREF))[t] = s[t] - pc;
    if (t == DICT/32 - 1){
        int nd = s[t];
        int ndpad = (nd + 63) & ~63;
        if (ndpad > SAUX) ndpad = SAUX;      // compact-buffer cap
        int* meta = (int*)(ws + WS_META);
        meta[0] = nd; meta[1] = ndpad; meta[2] = ndpad >> 6;
        meta[3] = ((ndpad >> 6) + AUX_SPLIT - 1) / AUX_SPLIT;
        int tot = 0;
        #pragma unroll
        for (int wv=0; wv<12; wv++) tot += c12[wv];
        ws[WS_ACC+4] = (float)tot;
        ((int*)ws)[WS_ACC+5] = (nd > 0) ? 1 : 0;
    }
}

// ---------------- kernel W+E1: wdt compaction AND aux select (LDS-staged) ----
__global__ __launch_bounds__(512) void auxprep_k(const unsigned short* __restrict__ actsb,
        unsigned short* __restrict__ wdt, unsigned short* __restrict__ auxc,
        float* __restrict__ ws){
    __shared__ unsigned s_db[DICT/32];
    __shared__ int      s_dp[DICT/32];
    __shared__ int      s_i16[16];
    __shared__ unsigned short s_out[SAUX];
    const int tid = threadIdx.x;
    for (int i=tid; i<DICT/32; i+=512){
        s_db[i] = ((const unsigned*)(ws + WS_DB))[i];
        s_dp[i] = ((const int*)(ws + WS_DPREF))[i];
    }
    const int nd    = ((const int*)(ws + WS_META))[0];
    const int ndpad = ((const int*)(ws + WS_META))[1];
    __syncthreads();
    if (blockIdx.x < DIN){
        const int n = blockIdx.x;
        unsigned short* row = wdt + (size_t)n*DICT;
        #pragma unroll
        for (int i=0;i<6;i++){
            u16x8 a = *(const u16x8*)&row[i*4096 + tid*8];
            int w = i*128 + (tid>>2);
            unsigned dbw = s_db[w]; int dpw = s_dp[w];
            #pragma unroll
            for (int e=0;e<8;e++){
                int bit = (tid&3)*8 + e;
                if ((dbw >> bit) & 1u){
                    int p = dpw + __popc(dbw & ((1u<<bit)-1u));
                    if (p < SAUX) s_out[p] = a[e];
                }
            }
        }
        for (int t2 = nd + tid; t2 < ndpad; t2 += 512) s_out[t2] = 0;
        __syncthreads();
        for (int i = tid*8; i < ndpad; i += 4096)
            *(u16x8*)&row[i] = *(const u16x8*)&s_out[i];
    } else {
        const int row = blockIdx.x - DIN;
        const unsigned short* arow = actsb + (size_t)row * DICT;
        // keys: bf16 bits if (dead && positive) else 0
        unsigned short key[NPT];
        #pragma unroll
        for (int i=0;i<6;i++){
            u16x8 v = *(const u16x8*)&arow[i*4096 + tid*8];
            unsigned dbw = s_db[i*128 + (tid>>2)];
            #pragma unroll
            for (int e=0;e<8;e++){
                unsigned short hv = v[e];
                key[i*8+e] = (((dbw >> ((tid&3)*8 + e)) & 1u) && hv) ? hv : 0;
            }
        }
        // 15-bit radix: prefix = 512th-largest key (0 if fewer than 512 positives)
        int par = 0;
        unsigned prefix = 0;
        for (int bit=14; bit>=0; bit--){
            unsigned cand = prefix | (1u<<bit);
            int c = 0;
            #pragma unroll
            for (int q=0;q<NPT;q++) c += (int)__popcll(__ballot((unsigned)key[q] >= cand));
            int tot = blk_count512_w(c, s_i16, par); par ^= 1;
            if (tot >= KA) prefix = cand;
        }
        unsigned thr = prefix ? prefix : 1u;   // all ties; all positives if <512
        // compacted masked write into LDS: s_out[rank(j)] = (key >= thr) ? key : 0
        #pragma unroll
        for (int i=0;i<6;i++){
            int w = i*128 + (tid>>2);
            unsigned dbw = s_db[w];
            int dpw = s_dp[w];
            #pragma unroll
            for (int e=0;e<8;e++){
                int bit = (tid&3)*8 + e;
                if ((dbw >> bit) & 1u){
                    int p = dpw + __popc(dbw & ((1u<<bit)-1u));
                    unsigned short kv = key[i*8+e];
                    if (p < SAUX) s_out[p] = ((unsigned)kv >= thr) ? kv : (unsigned short)0;
                }
            }
        }
        for (int t2 = nd + tid; t2 < ndpad; t2 += 512) s_out[t2] = 0;
        __syncthreads();
        unsigned short* crow = auxc + (size_t)row * SAUX;
        for (int i = tid*8; i < ndpad; i += 4096)
            *(u16x8*)&crow[i] = *(const u16x8*)&s_out[i];
    }
}

// ---------------- kernel E2+Z: aux GEMM ∥ zero+scatter sparse output ---------
__global__ __launch_bounds__(256) void auxgz_k(const unsigned short* __restrict__ Abf,
        const unsigned short* __restrict__ Bbf, float* __restrict__ ws,
        float* __restrict__ acts){
    __shared__ __align__(16) unsigned short As[128*64];
    __shared__ __align__(16) unsigned short Bs[128*64];
    const int tid = threadIdx.x;
    if (blockIdx.x >= AGB){
        const int row = blockIdx.x - AGB;
        float4 z = make_float4(0.f,0.f,0.f,0.f);
        float4* arow4 = (float4*)(acts + (size_t)row*DICT);
        #pragma unroll
        for (int i=0;i<24;i++) arow4[tid + 256*i] = z;
        __syncthreads();
        if (tid < KM){
            int j   = ((const int*)ws)[WS_SEL + (size_t)row*KM + tid];
            float v = ws[WS_SELV + (size_t)row*KM + tid];
            (acts + (size_t)row*DICT)[j] = v;
        }
        return;
    }
    const int nkt   = ((const int*)(ws + WS_META))[2];
    const int chunk = ((const int*)(ws + WS_META))[3];
    const int g = blockIdx.x;
    const int z = g & 7;
    const int s_ = g >> 3;             // 0..95
    const int m_t = s_ & 15;
    const int n_t = s_ >> 4;           // 0..5
    int t0 = z * chunk;
    int t1 = t0 + chunk; if (t1 > nkt) t1 = nkt;
    const int w = tid >> 6, lane = tid & 63;
    const int m0 = m_t*128, n0 = n_t*128;
    const int srow = lane >> 3;
    const int schunk = (lane & 7) ^ srow;
    const int wm = (w >> 1)*64, wn = (w & 1)*64;
    f32x4 acc[16];
    #pragma unroll
    for (int i=0;i<16;i++) acc[i] = (f32x4){0.f,0.f,0.f,0.f};
    for (int t = t0; t < t1; ++t){
        int kt = t*64;
        #pragma unroll
        for (int q=0;q<4;q++){
            int s = w*4 + q;
            int row = 8*s + srow;
            gld_lds16(Abf + (size_t)(m0+row)*SAUX + kt + schunk*8, &As[8*s*64]);
            gld_lds16(Bbf + (size_t)(n0+row)*DICT + kt + schunk*8, &Bs[8*s*64]);
        }
        __syncthreads();
        #pragma unroll
        for (int kk=0; kk<64; kk+=32){
            bf16x8 af[4], bfr[4];
            int ch = (kk>>3) + (lane>>4);
            #pragma unroll
            for (int i=0;i<4;i++){
                int row = wm + i*16 + (lane&15);
                af[i] = *(const bf16x8*)&As[row*64 + ((ch ^ (row&7))<<3)];
            }
            #pragma unroll
            for (int j=0;j<4;j++){
                int row = wn + j*16 + (lane&15);
                bfr[j] = *(const bf16x8*)&Bs[row*64 + ((ch ^ (row&7))<<3)];
            }
            #pragma unroll
            for (int i=0;i<4;i++)
                #pragma unroll
                for (int j=0;j<4;j++)
                    acc[i*4+j] = __builtin_amdgcn_mfma_f32_16x16x32_bf16(af[i], bfr[j], acc[i*4+j], 0,0,0);
        }
        __syncthreads();
    }
    float* buf = ws + ((z < 6) ? (WS_WETB + (size_t)z*BATCH*DIN)
                               : (z == 6 ? WS_YN : WS_XENC));
    #pragma unroll
    for (int i=0;i<4;i++){
        #pragma unroll
        for (int r=0;r<4;r++){
            int m = m0 + wm + i*16 + (lane>>4)*4 + r;
            float* crow = buf + (size_t)m*DIN + n0 + wn + (lane&15);
            #pragma unroll
            for (int j=0;j<4;j++) crow[j*16] = acc[i*4+j][r];
        }
    }
}

// ---------------- kernel E3: aux loss reduction (sums 8 split buffers) -------
__global__ __launch_bounds__(256) void auxloss_k(float* __restrict__ ws){
    __shared__ float s8[8];
    const float4* b0 = (const float4*)(ws + WS_WETB);
    const float4* b1 = (const float4*)(ws + WS_WETB + 1*(size_t)BATCH*DIN);
    const float4* b2 = (const float4*)(ws + WS_WETB + 2*(size_t)BATCH*DIN);
    const float4* b3 = (const float4*)(ws + WS_WETB + 3*(size_t)BATCH*DIN);
    const float4* b4 = (const float4*)(ws + WS_WETB + 4*(size_t)BATCH*DIN);
    const float4* b5 = (const float4*)(ws + WS_WETB + 5*(size_t)BATCH*DIN);
    const float4* b6 = (const float4*)(ws + WS_YN);
    const float4* b7 = (const float4*)(ws + WS_XENC);
    const float4* r4 = (const float4*)(ws + WS_RES);
    float s = 0.f;
    const size_t n4 = (size_t)BATCH*DIN/4;
    for (size_t i = (size_t)blockIdx.x*256 + threadIdx.x; i < n4; i += (size_t)gridDim.x*256){
        float4 a0 = b0[i], a1 = b1[i], a2 = b2[i], a3 = b3[i];
        float4 a4 = b4[i], a5 = b5[i], a6 = b6[i], a7 = b7[i];
        float4 rr = r4[i];
        float x0 = ((a0.x+a1.x)+(a2.x+a3.x))+((a4.x+a5.x)+(a6.x+a7.x)) - rr.x;
        float x1 = ((a0.y+a1.y)+(a2.y+a3.y))+((a4.y+a5.y)+(a6.y+a7.y)) - rr.y;
        float x2 = ((a0.z+a1.z)+(a2.z+a3.z))+((a4.z+a5.z)+(a6.z+a7.z)) - rr.z;
        float x3 = ((a0.w+a1.w)+(a2.w+a3.w))+((a4.w+a5.w)+(a6.w+a7.w)) - rr.w;
        s += x0*x0 + x1*x1 + x2*x2 + x3*x3;
    }
    float tot = blk_sum256(s, s8, 0);
    if (threadIdx.x == 0) atomicAdd(&ws[WS_ACC+3], tot);
}

// ---------------- kernel F: scalars ------------------------------------------
__global__ void finalize_k(const float* __restrict__ ws, float* __restrict__ out){
    if (threadIdx.x == 0){
        float l2   = ws[WS_ACC+0] / (float)((size_t)BATCH*DIN);
        float l1n  = ws[WS_ACC+1] / (float)BATCH;
        float l1l  = L1_COEFF * l1n;
        float l0   = ws[WS_ACC+2] / (float)BATCH;
        float auxm = AUX_PENALTY * (ws[WS_ACC+3] / (float)((size_t)BATCH*DIN));
        int any    = ((const int*)ws)[WS_ACC+5];
        float auxl = any ? auxm : 0.f;
        out[0] = l2 + l1l + auxl;
        out[1] = l2;
        out[2] = l1l;
        out[3] = l0;
        out[4] = l1n;
        out[5] = auxl;
        out[6] = ws[WS_ACC+4];
    }
}

extern "C" void kernel_launch(void* const* d_in, const int* in_sizes, int n_in,
                              void* d_out, int out_size, void* d_ws, size_t ws_size,
                              hipStream_t stream){
    const float* x_in = (const float*)d_in[0];
    const float* y_t  = (const float*)d_in[1];
    const float* nb   = (const float*)d_in[2];
    const float* Wenc = (const float*)d_in[3];
    const float* Wdec = (const float*)d_in[4];
    const float* bdec = (const float*)d_in[5];
    float* out  = (float*)d_out;
    float* ws   = (float*)d_ws;
    float* acts = out + (size_t)BATCH*DIN;                       // acts_sparse region
    float* scal = out + (size_t)BATCH*DIN + (size_t)BATCH*DICT;  // 7 scalars
    unsigned short* actsb = (unsigned short*)acts;               // bf16 acts (first half)

    unsigned short* xeb  = (unsigned short*)(ws + WS_XEB);
    float*          wetf = ws + WS_WETF;
    unsigned short* wetb = (unsigned short*)(ws + WS_WETB);
    unsigned short* wdt  = (unsigned short*)(ws + WS_WDB);       // Wdec^T bf16
    unsigned short* auxc = (unsigned short*)(ws + WS_WETF);      // compact aux acts (WETF reuse)

    prep_k<<<2*BATCH + (DICT/32)*(DIN/32), 256, 0, stream>>>(
        x_in, y_t, bdec, Wenc, Wdec, wetf, wetb, wdt, ws);
    gemm_mfma<<<(DICT/256)*(BATCH/256), 512, 0, stream>>>(xeb, wetb, actsb);
    topk_main<<<BATCH, 512, 0, stream>>>(actsb, wetf, Wdec, bdec, ws, out);
    deadscan_k<<<1, DICT/32, 0, stream>>>(nb, ws);
    auxprep_k<<<DIN + BATCH, 512, 0, stream>>>(actsb, wdt, auxc, ws);
    auxgz_k<<<AGB + BATCH, 256, 0, stream>>>(auxc, wdt, ws, acts);
    auxloss_k<<<256, 256, 0, stream>>>(ws);
    finalize_k<<<1, 64, 0, stream>>>(ws, scal);
}

// Round 8
// 839.763 us; speedup vs baseline: 1.0056x; 1.0056x over previous
//
#include <hip/hip_runtime.h>
#include <math.h>

#define BATCH 2048
#define DIN 768
#define DICT 24576
#define KM 32
#define KA 512
#define NPT 48            // DICT / 512 elements per thread
#define L1_COEFF 0.001f
#define AUX_PENALTY 0.03125f
#define CAND_MAX 128
#define CAND_DELTA 0.08f
#define AUX_SPLIT 8       // split-K factor for the aux GEMM
#define SAUX 18432        // compact-acts row stride (bf16); WETF region reuse
#define AGB ((DIN/128)*(BATCH/128)*AUX_SPLIT)   // 768 aux-gemm blocks

typedef __attribute__((ext_vector_type(8))) short bf16x8;
typedef __attribute__((ext_vector_type(8))) unsigned short u16x8;
typedef __attribute__((ext_vector_type(4))) float f32x4;

// ---------------- ws layout (float slots) ----------------
constexpr size_t WS_XENC   = 0;                              // BATCH*DIN f32 (x_enc; later aux split-7 buffer)
constexpr size_t WS_YN     = WS_XENC + (size_t)BATCH*DIN;    // BATCH*DIN (later aux split-6 buffer)
constexpr size_t WS_YMEAN  = WS_YN + (size_t)BATCH*DIN;      // BATCH
constexpr size_t WS_YSTD   = WS_YMEAN + BATCH;               // BATCH
constexpr size_t WS_RES    = WS_YSTD + BATCH;                // BATCH*DIN
constexpr size_t WS_NSEL   = WS_RES + (size_t)BATCH*DIN;     // BATCH (unused)
constexpr size_t WS_SEL    = WS_NSEL + BATCH;                // BATCH*KM (int)
constexpr size_t WS_SELV   = WS_SEL + (size_t)BATCH*KM;      // BATCH*KM (float, exact vals)
constexpr size_t WS_COLACT = WS_SELV + (size_t)BATCH*KM;     // DICT (int, cleared in prep_k)
constexpr size_t WS_ACC    = WS_COLACT + DICT;               // 8 (cleared in prep_k)
constexpr size_t WS_DB     = WS_ACC + 8;                     // DICT/32 words (dead bitmap)
constexpr size_t WS_XEB    = WS_DB + DICT/32;                // BATCH*DIN bf16 -> /2 slots
constexpr size_t WS_WETF   = WS_XEB + (size_t)BATCH*DIN/2;   // DICT*DIN f32 (Wenc^T; reused as compact aux acts)
constexpr size_t WS_WETB   = WS_WETF + (size_t)DICT*DIN;     // DICT*DIN bf16 (Wenc^T; later aux split bufs 0..5)
constexpr size_t WS_WDB    = WS_WETB + (size_t)DICT*DIN/2;   // DIN*DICT bf16 (Wdec^T, compacted in place)
// small int arrays live in the XEB region (xeb is dead after gemm_mfma):
constexpr size_t WS_DPREF  = WS_XEB + DICT/32;               // DICT/32 ints (exclusive prefix = rank base)
constexpr size_t WS_META   = WS_XEB + 2*(DICT/32);           // 8 ints: [0]=ND [1]=NDpad [2]=NKT [3]=chunk
// ACC: 0 l2_sum, 1 l1_sum, 2 l0_sum, 3 aux_sq, 4 numdead, 5 anydead(int)

__device__ __forceinline__ unsigned short f2b(float f){   // RNE fp32 -> bf16
    unsigned u = __float_as_uint(f);
    return (unsigned short)((u + 0x7fffu + ((u >> 16) & 1u)) >> 16);
}
__device__ __forceinline__ float b2f(unsigned short h){ return __uint_as_float(((unsigned)h) << 16); }

__device__ __forceinline__ void gld_lds16(const void* g, void* l){
    __builtin_amdgcn_global_load_lds(
        (const __attribute__((address_space(1))) unsigned int*)g,
        (__attribute__((address_space(3))) unsigned int*)l, 16, 0, 0);
}

// wave-uniform count (from ballot/popc) -> block total; ping-pong parity buffer
__device__ __forceinline__ int blk_count512_w(int cw, int* s16, int par){
    if ((threadIdx.x & 63) == 0) s16[par*8 + (threadIdx.x >> 6)] = cw;
    __syncthreads();
    int tot = 0;
    #pragma unroll
    for (int w=0; w<8; w++) tot += s16[par*8+w];
    return tot;
}
__device__ __forceinline__ float blk_sum512(float v, float* s16, int par){
    #pragma unroll
    for (int off=32; off; off>>=1) v += __shfl_down(v, off);
    if ((threadIdx.x & 63) == 0) s16[par*8 + (threadIdx.x >> 6)] = v;
    __syncthreads();
    float t = 0.f;
    #pragma unroll
    for (int w=0; w<8; w++) t += s16[par*8+w];
    return t;
}
__device__ __forceinline__ float blk_sum256(float v, float* s8, int par){
    #pragma unroll
    for (int off=32; off; off>>=1) v += __shfl_down(v, off);
    if ((threadIdx.x & 63) == 0) s8[par*4 + (threadIdx.x >> 6)] = v;
    __syncthreads();
    float t = 0.f;
    #pragma unroll
    for (int w=0; w<4; w++) t += s8[par*4+w];
    return t;
}

// ---------------- kernel A+P: normalize rows AND both weight transposes ------
// Transpose branch: 64x64 tiles, float4 reads (1KB/wave), LDS [64][65] stage,
// float4/ushort4 writes (segments 256B f32 / 128B bf16; was 128B/64B scalar).
__global__ __launch_bounds__(256) void prep_k(const float* __restrict__ x,
        const float* __restrict__ y, const float* __restrict__ bdec,
        const float* __restrict__ We, const float* __restrict__ Wd,
        float* __restrict__ Tf, unsigned short* __restrict__ Tb,
        unsigned short* __restrict__ Td, float* __restrict__ ws){
    __shared__ float s8[8];
    __shared__ float t1[64][65];
    __shared__ float t2[64][65];
    const int tid = threadIdx.x;
    if (blockIdx.x < 2*BATCH){
        int b = blockIdx.x; bool isy = b >= BATCH; int row = isy ? b - BATCH : b;
        if (b < 8){   // clear colact + ACC (read only by later launches)
            float* dst = ws + WS_COLACT;
            for (int i = b*256 + tid; i < DICT + 8; i += 2048) dst[i] = 0.f;
        }
        const float* src = (isy ? y : x) + (size_t)row*DIN;
        float v0 = src[tid], v1 = src[tid+256], v2 = src[tid+512];
        float s = blk_sum256(v0+v1+v2, s8, 0);
        float mean = s * (1.f/(float)DIN);
        float d0 = v0-mean, d1 = v1-mean, d2 = v2-mean;
        float vs = blk_sum256(d0*d0+d1*d1+d2*d2, s8, 1);
        float sd = sqrtf(vs / (float)(DIN-1));
        float inv = 1.f / (sd + 1e-5f);
        if (isy){
            float* yn = ws + WS_YN + (size_t)row*DIN;
            yn[tid] = d0*inv; yn[tid+256] = d1*inv; yn[tid+512] = d2*inv;
            if (tid==0){ ws[WS_YMEAN+row] = mean; ws[WS_YSTD+row] = sd; }
        } else {
            float* xe = ws + WS_XENC + (size_t)row*DIN;
            unsigned short* xeb = (unsigned short*)(ws + WS_XEB) + (size_t)row*DIN;
            float e0 = d0*inv - bdec[tid];
            float e1 = d1*inv - bdec[tid+256];
            float e2 = d2*inv - bdec[tid+512];
            xe[tid] = e0; xe[tid+256] = e1; xe[tid+512] = e2;
            xeb[tid] = f2b(e0); xeb[tid+256] = f2b(e1); xeb[tid+512] = f2b(e2);
        }
    } else {
        int t = blockIdx.x - 2*BATCH;
        int bx = t % (DICT/64), by = t / (DICT/64);
        int a0 = bx*64, k0 = by*64;                 // a0 over DICT, k0 over DIN
        const int r = tid >> 4;                     // 0..15
        const int c4 = tid & 15;                    // 4-col group
        // t1[k_local][a_local] = We[k][a];  t2[a_local][k_local] = Wd[a][k]
        #pragma unroll
        for (int p=0;p<4;p++){
            int row = p*16 + r;
            float4 a = *(const float4*)&We[(size_t)(k0+row)*DICT + a0 + c4*4];
            *(float4*)&t1[row][c4*4] = a;
            float4 b = *(const float4*)&Wd[(size_t)(a0+row)*DIN + k0 + c4*4];
            *(float4*)&t2[row][c4*4] = b;
        }
        __syncthreads();
        #pragma unroll
        for (int p=0;p<4;p++){
            int row = p*16 + r;
            // Tf/Tb row = a0+row, cols k0 + c4*4 (contiguous in k)
            float v0 = t1[c4*4+0][row], v1 = t1[c4*4+1][row];
            float v2 = t1[c4*4+2][row], v3 = t1[c4*4+3][row];
            *(float4*)&Tf[(size_t)(a0+row)*DIN + k0 + c4*4] = make_float4(v0,v1,v2,v3);
            ushort4 ob; ob.x=f2b(v0); ob.y=f2b(v1); ob.z=f2b(v2); ob.w=f2b(v3);
            *(ushort4*)&Tb[(size_t)(a0+row)*DIN + k0 + c4*4] = ob;
            // Td row = k0+row, cols a0 + c4*4 (contiguous in n)
            float w0 = t2[c4*4+0][row], w1 = t2[c4*4+1][row];
            float w2 = t2[c4*4+2][row], w3 = t2[c4*4+3][row];
            ushort4 od; od.x=f2b(w0); od.y=f2b(w1); od.z=f2b(w2); od.w=f2b(w3);
            *(ushort4*)&Td[(size_t)(k0+row)*DICT + a0 + c4*4] = od;
        }
    }
}

// ---------------- kernel B: 256x256-tile deep-pipelined bf16 MFMA GEMM -------
// 8 waves (2x4), 128KB double-buffered LDS, xor-8 row swizzle (0-conflict).
__global__ __launch_bounds__(512, 2) void gemm_mfma(const unsigned short* __restrict__ Abf,
        const unsigned short* __restrict__ Bbf, unsigned short* __restrict__ C){
    __shared__ __align__(16) unsigned short As2[2][16384];   // 2 x 256rows x 64
    __shared__ __align__(16) unsigned short Bs2[2][16384];
    const int tid = threadIdx.x;
    const int w = tid >> 6, lane = tid & 63;
    const int wr = w >> 2, wc = w & 3;            // 2 x 4 wave grid
    const int g = blockIdx.x;
    const int xcd = g & 7;
    const int s_ = g >> 3;                        // 0..95
    const int m_t = s_ & 7;                       // 8 M-tiles of 256
    const int n_t = xcd + 8*(s_ >> 3);            // 12 n-panels per XCD
    const int m0 = m_t*256, n0 = n_t*256;
    const int srow = lane >> 3;                   // 0..7 row within staging stripe
    const int schunk = (lane & 7) ^ srow;         // source chunk (xor swizzle)
    const int l15 = lane & 15, l4 = lane >> 4;

    f32x4 acc[8][4];
    #pragma unroll
    for (int i=0;i<8;i++)
        #pragma unroll
        for (int j=0;j<4;j++) acc[i][j] = (f32x4){0.f,0.f,0.f,0.f};

    #define STAGE_Q(b,kt,q) { \
        int sa = w*4 + (q); \
        gld_lds16(Abf + (size_t)(m0 + 8*sa + srow)*DIN + (kt) + schunk*8, &As2[b][8*sa*64]); \
        gld_lds16(Bbf + (size_t)(n0 + 8*sa + srow)*DIN + (kt) + schunk*8, &Bs2[b][8*sa*64]); }

    #pragma unroll
    for (int q=0;q<4;q++) STAGE_Q(0, 0, q);
    asm volatile("s_waitcnt vmcnt(0)" ::: "memory");
    __builtin_amdgcn_s_barrier();

    for (int t = 0; t < 12; ++t){
        const int cur = t & 1, nb = cur ^ 1;
        const unsigned short* Ac = As2[cur];
        const unsigned short* Bc = Bs2[cur];
        const int ktn = (t+1)*64;
        const bool more = t < 11;
        bf16x8 af[4], bfr[4];
        // ---- phase 0: kk=0, A i=0..3 (+ B for kk=0) ----
        if (more) STAGE_Q(nb, ktn, 0);
        {
            int ch = l4;
            #pragma unroll
            for (int j=0;j<4;j++){
                int row = wc*64 + j*16 + l15;
                bfr[j] = *(const bf16x8*)&Bc[row*64 + ((ch ^ (row&7))<<3)];
            }
            #pragma unroll
            for (int i=0;i<4;i++){
                int row = wr*128 + i*16 + l15;
                af[i] = *(const bf16x8*)&Ac[row*64 + ((ch ^ (row&7))<<3)];
            }
        }
        __builtin_amdgcn_s_barrier();
        __builtin_amdgcn_s_setprio(1);
        #pragma unroll
        for (int i=0;i<4;i++)
            #pragma unroll
            for (int j=0;j<4;j++)
                acc[i][j] = __builtin_amdgcn_mfma_f32_16x16x32_bf16(af[i], bfr[j], acc[i][j], 0,0,0);
        __builtin_amdgcn_s_setprio(0);
        // ---- phase 1: kk=0, A i=4..7 (reuse bfr) ----
        if (more) STAGE_Q(nb, ktn, 1);
        {
            int ch = l4;
            #pragma unroll
            for (int i=0;i<4;i++){
                int row = wr*128 + (i+4)*16 + l15;
                af[i] = *(const bf16x8*)&Ac[row*64 + ((ch ^ (row&7))<<3)];
            }
        }
        __builtin_amdgcn_s_barrier();
        __builtin_amdgcn_s_setprio(1);
        #pragma unroll
        for (int i=0;i<4;i++)
            #pragma unroll
            for (int j=0;j<4;j++)
                acc[i+4][j] = __builtin_amdgcn_mfma_f32_16x16x32_bf16(af[i], bfr[j], acc[i+4][j], 0,0,0);
        __builtin_amdgcn_s_setprio(0);
        // ---- phase 2: kk=32, A i=0..3 (+ B for kk=32) ----
        if (more) STAGE_Q(nb, ktn, 2);
        {
            int ch = 4 + l4;
            #pragma unroll
            for (int j=0;j<4;j++){
                int row = wc*64 + j*16 + l15;
                bfr[j] = *(const bf16x8*)&Bc[row*64 + ((ch ^ (row&7))<<3)];
            }
            #pragma unroll
            for (int i=0;i<4;i++){
                int row = wr*128 + i*16 + l15;
                af[i] = *(const bf16x8*)&Ac[row*64 + ((ch ^ (row&7))<<3)];
            }
        }
        __builtin_amdgcn_s_barrier();
        __builtin_amdgcn_s_setprio(1);
        #pragma unroll
        for (int i=0;i<4;i++)
            #pragma unroll
            for (int j=0;j<4;j++)
                acc[i][j] = __builtin_amdgcn_mfma_f32_16x16x32_bf16(af[i], bfr[j], acc[i][j], 0,0,0);
        __builtin_amdgcn_s_setprio(0);
        // ---- phase 3: kk=32, A i=4..7 ----
        if (more) STAGE_Q(nb, ktn, 3);
        {
            int ch = 4 + l4;
            #pragma unroll
            for (int i=0;i<4;i++){
                int row = wr*128 + (i+4)*16 + l15;
                af[i] = *(const bf16x8*)&Ac[row*64 + ((ch ^ (row&7))<<3)];
            }
        }
        __builtin_amdgcn_s_barrier();
        __builtin_amdgcn_s_setprio(1);
        #pragma unroll
        for (int i=0;i<4;i++)
            #pragma unroll
            for (int j=0;j<4;j++)
                acc[i+4][j] = __builtin_amdgcn_mfma_f32_16x16x32_bf16(af[i], bfr[j], acc[i+4][j], 0,0,0);
        __builtin_amdgcn_s_setprio(0);
        // ---- tile boundary: drain next-tile loads (issued ~4 phases ago) ----
        asm volatile("s_waitcnt vmcnt(0)" ::: "memory");
        __builtin_amdgcn_s_barrier();
    }
    #undef STAGE_Q
    // C/D layout: col = lane&15, row = (lane>>4)*4 + reg.  +0.0f kills -0.
    #pragma unroll
    for (int i=0;i<8;i++){
        #pragma unroll
        for (int r=0;r<4;r++){
            int m = m0 + wr*128 + i*16 + l4*4 + r;
            unsigned short* crow = C + (size_t)m*DICT + n0 + wc*64 + l15;
            #pragma unroll
            for (int j=0;j<4;j++)
                crow[j*16] = f2b(fmaxf(acc[i][j][r], 0.f) + 0.0f);
        }
    }
}

// ---------------- kernel C1: block radix -> exact refine -> top-32 -----------
__global__ __launch_bounds__(512) void topk_main(const unsigned short* __restrict__ actsb,
        const float* __restrict__ WeTf, const float* __restrict__ Wdec,
        const float* __restrict__ bdec, float* __restrict__ ws,
        float* __restrict__ ypred_out){
    const int row = blockIdx.x, tid = threadIdx.x;
    const int lane = tid & 63, wid = tid >> 6;
    __shared__ int   s_i16[16];
    __shared__ float s_f16[16];
    __shared__ float s_x[DIN];
    __shared__ int   s_ci[CAND_MAX];
    __shared__ float s_cv[CAND_MAX];
    __shared__ int   s_li[KM];
    __shared__ float s_lv[KM];
    __shared__ int   s_n, s_m;
    const unsigned short* arow = actsb + (size_t)row * DICT;
    const float* xrow = ws + WS_XENC + (size_t)row * DIN;
    unsigned short h[NPT];
    #pragma unroll
    for (int i=0;i<6;i++){
        u16x8 v = *(const u16x8*)&arow[i*4096 + tid*8];
        #pragma unroll
        for (int e=0;e<8;e++) h[i*8+e] = v[e];
    }
    s_x[tid] = xrow[tid];
    if (tid < DIN-512) s_x[tid+512] = xrow[tid+512];
    if (tid == 0){ s_n = 0; s_m = 0; }

    // 15-bit block radix on bf16 pattern: prefix = 32nd-largest stored value.
    int par = 0;
    unsigned prefix = 0;
    for (int bit=14; bit>=0; bit--){
        unsigned cand = prefix | (1u<<bit);
        int c = 0;
        #pragma unroll
        for (int q=0;q<NPT;q++) c += (int)__popcll(__ballot((unsigned)h[q] >= cand));
        int tot = blk_count512_w(c, s_i16, par); par ^= 1;
        if (tot >= KM) prefix = cand;
    }
    float tc = b2f((unsigned short)prefix) - CAND_DELTA;  // candidate threshold
    #pragma unroll
    for (int q=0;q<NPT;q++){
        if (b2f(h[q]) > tc){
            int p = atomicAdd(&s_n, 1);
            if (p < CAND_MAX) s_ci[p] = (q>>3)*4096 + tid*8 + (q&7);
        }
    }
    __syncthreads();
    int nc = s_n; if (nc > CAND_MAX) nc = CAND_MAX;
    // exact fp32 recompute of candidates (wave per candidate, strided)
    for (int c = wid; c < nc; c += 8){
        const float* wr = WeTf + (size_t)s_ci[c]*DIN;
        float p = 0.f;
        #pragma unroll
        for (int t=0; t<12; t++) p = fmaf(s_x[lane + 64*t], wr[lane + 64*t], p);
        #pragma unroll
        for (int off=32; off; off>>=1) p += __shfl_down(p, off);
        if (lane == 0) s_cv[c] = fmaxf(p, 0.f);
    }
    __syncthreads();
    // exact top-32 among candidates, stable (value desc, index asc)
    if (tid < nc){
        float vi = s_cv[tid]; int ii = s_ci[tid];
        int rank = 0;
        for (int j=0; j<nc; j++){
            float vj = s_cv[j];
            rank += (vj > vi) || (vj == vi && s_ci[j] < ii);
        }
        if (rank < KM){
            int p = atomicAdd(&s_m, 1);
            s_li[p] = ii; s_lv[p] = vi;
        }
    }
    __syncthreads();
    if (tid < KM){
        ((int*)ws)[WS_COLACT + s_li[tid]] = 1;
        ((int*)ws)[WS_SEL  + (size_t)row*KM + tid] = s_li[tid];
        ws[WS_SELV + (size_t)row*KM + tid] = s_lv[tid];
    }
    if (tid == 0){
        float l1 = 0.f; int l0 = 0;
        for (int l=0;l<KM;l++){ l1 += s_lv[l]; l0 += (s_lv[l] > 0.f); }
        atomicAdd(&ws[WS_ACC+1], l1);
        atomicAdd(&ws[WS_ACC+2], (float)l0);
    }
    __syncthreads();
    float ym = ws[WS_YMEAN+row], ys = ws[WS_YSTD+row];
    float l2loc = 0.f;
    for (int c = tid; c < DIN; c += 512){
        float acc = bdec[c];
        #pragma unroll 4
        for (int l=0;l<KM;l++) acc = fmaf(s_lv[l], Wdec[(size_t)s_li[l]*DIN + c], acc);
        float ynv = ws[WS_YN + (size_t)row*DIN + c];
        float d = acc - ynv;
        l2loc += d*d;
        ws[WS_RES + (size_t)row*DIN + c] = ynv - acc;
        ypred_out[(size_t)row*DIN + c] = fmaf(acc, ys, ym);
    }
    float l2t = blk_sum512(l2loc, s_f16, 0);
    if (tid==0) atomicAdd(&ws[WS_ACC+0], l2t);
}

// ---------------- kernel D+S: dead bookkeeping + popcount prefix scan --------
__global__ __launch_bounds__(768) void deadscan_k(const float* __restrict__ nb,
        float* __restrict__ ws){
    __shared__ int s[DICT/32];
    __shared__ int c12[12];
    const int t = threadIdx.x;
    const int* colact = (const int*)ws + WS_COLACT;
    unsigned bits = 0; int cgt = 0;
    const int base = t*32;
    #pragma unroll 8
    for (int b=0;b<32;b++){
        int j = base + b;
        float nbn = colact[j] ? 0.f : nb[j] + 1.f;
        bits |= (nbn >= 100.f ? 1u : 0u) << b;
        cgt  += (nbn > 100.f) ? 1 : 0;
    }
    ((unsigned*)(ws + WS_DB))[t] = bits;
    int pc = __popc(bits);
    s[t] = pc;
    #pragma unroll
    for (int off=32; off; off>>=1) cgt += __shfl_down(cgt, off);
    if ((t & 63) == 0) c12[t >> 6] = cgt;
    __syncthreads();
    for (int off=1; off<DICT/32; off<<=1){
        int v = (t >= off) ? s[t-off] : 0;
        __syncthreads();
        s[t] += v;
        __syncthreads();
    }
    ((int*)(ws + WS_DPREF))[t] = s[t] - pc;
    if (t == DICT/32 - 1){
        int nd = s[t];
        int ndpad = (nd + 63) & ~63;
        if (ndpad > SAUX) ndpad = SAUX;      // compact-buffer cap
        int* meta = (int*)(ws + WS_META);
        meta[0] = nd; meta[1] = ndpad; meta[2] = ndpad >> 6;
        meta[3] = ((ndpad >> 6) + AUX_SPLIT - 1) / AUX_SPLIT;
        int tot = 0;
        #pragma unroll
        for (int wv=0; wv<12; wv++) tot += c12[wv];
        ws[WS_ACC+4] = (float)tot;
        ((int*)ws)[WS_ACC+5] = (nd > 0) ? 1 : 0;
    }
}

// ---------------- kernel W+E1: wdt compaction AND aux select (LDS-staged) ----
__global__ __launch_bounds__(512) void auxprep_k(const unsigned short* __restrict__ actsb,
        unsigned short* __restrict__ wdt, unsigned short* __restrict__ auxc,
        float* __restrict__ ws){
    __shared__ unsigned s_db[DICT/32];
    __shared__ int      s_dp[DICT/32];
    __shared__ int      s_i16[16];
    __shared__ unsigned short s_out[SAUX];
    const int tid = threadIdx.x;
    for (int i=tid; i<DICT/32; i+=512){
        s_db[i] = ((const unsigned*)(ws + WS_DB))[i];
        s_dp[i] = ((const int*)(ws + WS_DPREF))[i];
    }
    const int nd    = ((const int*)(ws + WS_META))[0];
    const int ndpad = ((const int*)(ws + WS_META))[1];
    __syncthreads();
    if (blockIdx.x < DIN){
        const int n = blockIdx.x;
        unsigned short* row = wdt + (size_t)n*DICT;
        #pragma unroll
        for (int i=0;i<6;i++){
            u16x8 a = *(const u16x8*)&row[i*4096 + tid*8];
            int w = i*128 + (tid>>2);
            unsigned dbw = s_db[w]; int dpw = s_dp[w];
            #pragma unroll
            for (int e=0;e<8;e++){
                int bit = (tid&3)*8 + e;
                if ((dbw >> bit) & 1u){
                    int p = dpw + __popc(dbw & ((1u<<bit)-1u));
                    if (p < SAUX) s_out[p] = a[e];
                }
            }
        }
        for (int t2 = nd + tid; t2 < ndpad; t2 += 512) s_out[t2] = 0;
        __syncthreads();
        for (int i = tid*8; i < ndpad; i += 4096)
            *(u16x8*)&row[i] = *(const u16x8*)&s_out[i];
    } else {
        const int row = blockIdx.x - DIN;
        const unsigned short* arow = actsb + (size_t)row * DICT;
        // keys: bf16 bits if (dead && positive) else 0
        unsigned short key[NPT];
        #pragma unroll
        for (int i=0;i<6;i++){
            u16x8 v = *(const u16x8*)&arow[i*4096 + tid*8];
            unsigned dbw = s_db[i*128 + (tid>>2)];
            #pragma unroll
            for (int e=0;e<8;e++){
                unsigned short hv = v[e];
                key[i*8+e] = (((dbw >> ((tid&3)*8 + e)) & 1u) && hv) ? hv : 0;
            }
        }
        // 15-bit radix: prefix = 512th-largest key (0 if fewer than 512 positives)
        int par = 0;
        unsigned prefix = 0;
        for (int bit=14; bit>=0; bit--){
            unsigned cand = prefix | (1u<<bit);
            int c = 0;
            #pragma unroll
            for (int q=0;q<NPT;q++) c += (int)__popcll(__ballot((unsigned)key[q] >= cand));
            int tot = blk_count512_w(c, s_i16, par); par ^= 1;
            if (tot >= KA) prefix = cand;
        }
        unsigned thr = prefix ? prefix : 1u;   // all ties; all positives if <512
        // compacted masked write into LDS: s_out[rank(j)] = (key >= thr) ? key : 0
        #pragma unroll
        for (int i=0;i<6;i++){
            int w = i*128 + (tid>>2);
            unsigned dbw = s_db[w];
            int dpw = s_dp[w];
            #pragma unroll
            for (int e=0;e<8;e++){
                int bit = (tid&3)*8 + e;
                if ((dbw >> bit) & 1u){
                    int p = dpw + __popc(dbw & ((1u<<bit)-1u));
                    unsigned short kv = key[i*8+e];
                    if (p < SAUX) s_out[p] = ((unsigned)kv >= thr) ? kv : (unsigned short)0;
                }
            }
        }
        for (int t2 = nd + tid; t2 < ndpad; t2 += 512) s_out[t2] = 0;
        __syncthreads();
        unsigned short* crow = auxc + (size_t)row * SAUX;
        for (int i = tid*8; i < ndpad; i += 4096)
            *(u16x8*)&crow[i] = *(const u16x8*)&s_out[i];
    }
}

// ---------------- kernel E2+Z: aux GEMM ∥ zero+scatter sparse output ---------
__global__ __launch_bounds__(256) void auxgz_k(const unsigned short* __restrict__ Abf,
        const unsigned short* __restrict__ Bbf, float* __restrict__ ws,
        float* __restrict__ acts){
    __shared__ __align__(16) unsigned short As[128*64];
    __shared__ __align__(16) unsigned short Bs[128*64];
    const int tid = threadIdx.x;
    if (blockIdx.x >= AGB){
        const int row = blockIdx.x - AGB;
        float4 z = make_float4(0.f,0.f,0.f,0.f);
        float4* arow4 = (float4*)(acts + (size_t)row*DICT);
        #pragma unroll
        for (int i=0;i<24;i++) arow4[tid + 256*i] = z;
        __syncthreads();
        if (tid < KM){
            int j   = ((const int*)ws)[WS_SEL + (size_t)row*KM + tid];
            float v = ws[WS_SELV + (size_t)row*KM + tid];
            (acts + (size_t)row*DICT)[j] = v;
        }
        return;
    }
    const int nkt   = ((const int*)(ws + WS_META))[2];
    const int chunk = ((const int*)(ws + WS_META))[3];
    const int g = blockIdx.x;
    const int z = g & 7;
    const int s_ = g >> 3;             // 0..95
    const int m_t = s_ & 15;
    const int n_t = s_ >> 4;           // 0..5
    int t0 = z * chunk;
    int t1 = t0 + chunk; if (t1 > nkt) t1 = nkt;
    const int w = tid >> 6, lane = tid & 63;
    const int m0 = m_t*128, n0 = n_t*128;
    const int srow = lane >> 3;
    const int schunk = (lane & 7) ^ srow;
    const int wm = (w >> 1)*64, wn = (w & 1)*64;
    f32x4 acc[16];
    #pragma unroll
    for (int i=0;i<16;i++) acc[i] = (f32x4){0.f,0.f,0.f,0.f};
    for (int t = t0; t < t1; ++t){
        int kt = t*64;
        #pragma unroll
        for (int q=0;q<4;q++){
            int s = w*4 + q;
            int row = 8*s + srow;
            gld_lds16(Abf + (size_t)(m0+row)*SAUX + kt + schunk*8, &As[8*s*64]);
            gld_lds16(Bbf + (size_t)(n0+row)*DICT + kt + schunk*8, &Bs[8*s*64]);
        }
        __syncthreads();
        #pragma unroll
        for (int kk=0; kk<64; kk+=32){
            bf16x8 af[4], bfr[4];
            int ch = (kk>>3) + (lane>>4);
            #pragma unroll
            for (int i=0;i<4;i++){
                int row = wm + i*16 + (lane&15);
                af[i] = *(const bf16x8*)&As[row*64 + ((ch ^ (row&7))<<3)];
            }
            #pragma unroll
            for (int j=0;j<4;j++){
                int row = wn + j*16 + (lane&15);
                bfr[j] = *(const bf16x8*)&Bs[row*64 + ((ch ^ (row&7))<<3)];
            }
            #pragma unroll
            for (int i=0;i<4;i++)
                #pragma unroll
                for (int j=0;j<4;j++)
                    acc[i*4+j] = __builtin_amdgcn_mfma_f32_16x16x32_bf16(af[i], bfr[j], acc[i*4+j], 0,0,0);
        }
        __syncthreads();
    }
    float* buf = ws + ((z < 6) ? (WS_WETB + (size_t)z*BATCH*DIN)
                               : (z == 6 ? WS_YN : WS_XENC));
    #pragma unroll
    for (int i=0;i<4;i++){
        #pragma unroll
        for (int r=0;r<4;r++){
            int m = m0 + wm + i*16 + (lane>>4)*4 + r;
            float* crow = buf + (size_t)m*DIN + n0 + wn + (lane&15);
            #pragma unroll
            for (int j=0;j<4;j++) crow[j*16] = acc[i*4+j][r];
        }
    }
}

// ---------------- kernel E3: aux loss reduction (sums 8 split buffers) -------
__global__ __launch_bounds__(256) void auxloss_k(float* __restrict__ ws){
    __shared__ float s8[8];
    const float4* b0 = (const float4*)(ws + WS_WETB);
    const float4* b1 = (const float4*)(ws + WS_WETB + 1*(size_t)BATCH*DIN);
    const float4* b2 = (const float4*)(ws + WS_WETB + 2*(size_t)BATCH*DIN);
    const float4* b3 = (const float4*)(ws + WS_WETB + 3*(size_t)BATCH*DIN);
    const float4* b4 = (const float4*)(ws + WS_WETB + 4*(size_t)BATCH*DIN);
    const float4* b5 = (const float4*)(ws + WS_WETB + 5*(size_t)BATCH*DIN);
    const float4* b6 = (const float4*)(ws + WS_YN);
    const float4* b7 = (const float4*)(ws + WS_XENC);
    const float4* r4 = (const float4*)(ws + WS_RES);
    float s = 0.f;
    const size_t n4 = (size_t)BATCH*DIN/4;
    for (size_t i = (size_t)blockIdx.x*256 + threadIdx.x; i < n4; i += (size_t)gridDim.x*256){
        float4 a0 = b0[i], a1 = b1[i], a2 = b2[i], a3 = b3[i];
        float4 a4 = b4[i], a5 = b5[i], a6 = b6[i], a7 = b7[i];
        float4 rr = r4[i];
        float x0 = ((a0.x+a1.x)+(a2.x+a3.x))+((a4.x+a5.x)+(a6.x+a7.x)) - rr.x;
        float x1 = ((a0.y+a1.y)+(a2.y+a3.y))+((a4.y+a5.y)+(a6.y+a7.y)) - rr.y;
        float x2 = ((a0.z+a1.z)+(a2.z+a3.z))+((a4.z+a5.z)+(a6.z+a7.z)) - rr.z;
        float x3 = ((a0.w+a1.w)+(a2.w+a3.w))+((a4.w+a5.w)+(a6.w+a7.w)) - rr.w;
        s += x0*x0 + x1*x1 + x2*x2 + x3*x3;
    }
    float tot = blk_sum256(s, s8, 0);
    if (threadIdx.x == 0) atomicAdd(&ws[WS_ACC+3], tot);
}

// ---------------- kernel F: scalars ------------------------------------------
__global__ void finalize_k(const float* __restrict__ ws, float* __restrict__ out){
    if (threadIdx.x == 0){
        float l2   = ws[WS_ACC+0] / (float)((size_t)BATCH*DIN);
        float l1n  = ws[WS_ACC+1] / (float)BATCH;
        float l1l  = L1_COEFF * l1n;
        float l0   = ws[WS_ACC+2] / (float)BATCH;
        float auxm = AUX_PENALTY * (ws[WS_ACC+3] / (float)((size_t)BATCH*DIN));
        int any    = ((const int*)ws)[WS_ACC+5];
        float auxl = any ? auxm : 0.f;
        out[0] = l2 + l1l + auxl;
        out[1] = l2;
        out[2] = l1l;
        out[3] = l0;
        out[4] = l1n;
        out[5] = auxl;
        out[6] = ws[WS_ACC+4];
    }
}

extern "C" void kernel_launch(void* const* d_in, const int* in_sizes, int n_in,
                              void* d_out, int out_size, void* d_ws, size_t ws_size,
                              hipStream_t stream){
    const float* x_in = (const float*)d_in[0];
    const float* y_t  = (const float*)d_in[1];
    const float* nb   = (const float*)d_in[2];
    const float* Wenc = (const float*)d_in[3];
    const float* Wdec = (const float*)d_in[4];
    const float* bdec = (const float*)d_in[5];
    float* out  = (float*)d_out;
    float* ws   = (float*)d_ws;
    float* acts = out + (size_t)BATCH*DIN;                       // acts_sparse region
    float* scal = out + (size_t)BATCH*DIN + (size_t)BATCH*DICT;  // 7 scalars
    unsigned short* actsb = (unsigned short*)acts;               // bf16 acts (first half)

    unsigned short* xeb  = (unsigned short*)(ws + WS_XEB);
    float*          wetf = ws + WS_WETF;
    unsigned short* wetb = (unsigned short*)(ws + WS_WETB);
    unsigned short* wdt  = (unsigned short*)(ws + WS_WDB);       // Wdec^T bf16
    unsigned short* auxc = (unsigned short*)(ws + WS_WETF);      // compact aux acts (WETF reuse)

    prep_k<<<2*BATCH + (DICT/64)*(DIN/64), 256, 0, stream>>>(
        x_in, y_t, bdec, Wenc, Wdec, wetf, wetb, wdt, ws);
    gemm_mfma<<<(DICT/256)*(BATCH/256), 512, 0, stream>>>(xeb, wetb, actsb);
    topk_main<<<BATCH, 512, 0, stream>>>(actsb, wetf, Wdec, bdec, ws, out);
    deadscan_k<<<1, DICT/32, 0, stream>>>(nb, ws);
    auxprep_k<<<DIN + BATCH, 512, 0, stream>>>(actsb, wdt, auxc, ws);
    auxgz_k<<<AGB + BATCH, 256, 0, stream>>>(auxc, wdt, ws, acts);
    auxloss_k<<<256, 256, 0, stream>>>(ws);
    finalize_k<<<1, 64, 0, stream>>>(ws, scal);
}